// Round 17
// baseline (46.183 us; speedup 1.0000x reference)
//
#include <hip/hip_runtime.h>
#include <stdint.h>

#define K_DIM 1024
#define M_TOT 16384
#define BM 128
#define BN 128
#define BK 64

typedef __attribute__((ext_vector_type(8))) short bf16x8;
typedef __attribute__((ext_vector_type(4))) float f32x4;
typedef __attribute__((ext_vector_type(8))) unsigned short u16x8;

__device__ inline uint16_t f2bf(float f) {
    union { float f; uint32_t u; } v; v.f = f;
    return (uint16_t)((v.u + 0x7fffu + ((v.u >> 16) & 1u)) >> 16);
}

// ---- x (16M f32) -> bf16 (only used by the 2048 fallback path) ----
__global__ void cvt_x_kernel(const float* __restrict__ x, uint16_t* __restrict__ xb) {
    const size_t n8 = (size_t)M_TOT * K_DIM / 8;
    for (size_t i = (size_t)blockIdx.x * blockDim.x + threadIdx.x; i < n8;
         i += (size_t)gridDim.x * blockDim.x) {
        const float4* s = (const float4*)x + i * 2;
        float4 a = s[0], b = s[1];
        u16x8 v;
        v[0] = f2bf(a.x); v[1] = f2bf(a.y); v[2] = f2bf(a.z); v[3] = f2bf(a.w);
        v[4] = f2bf(b.x); v[5] = f2bf(b.y); v[6] = f2bf(b.z); v[7] = f2bf(b.w);
        *(u16x8*)(xb + i * 8) = v;
    }
}

// ---- quarter weights: W[k][s] = cos(2*pi*k*s/1024), k,s in [0,512) ----
__global__ void build_wq_kernel(const float* __restrict__ wcos, uint16_t* __restrict__ W) {
    int i = blockIdx.x * blockDim.x + threadIdx.x;   // 32768 threads
    int k = i >> 6;            // 512 rows
    int sc = (i & 63) * 8;     // cols 0..511
    const float4* c = (const float4*)(wcos + (size_t)k * K_DIM + sc);
    float4 c0 = c[0], c1 = c[1];
    u16x8 vc;
    vc[0] = f2bf(c0.x); vc[1] = f2bf(c0.y); vc[2] = f2bf(c0.z); vc[3] = f2bf(c0.w);
    vc[4] = f2bf(c1.x); vc[5] = f2bf(c1.y); vc[6] = f2bf(c1.z); vc[7] = f2bf(c1.w);
    *(u16x8*)(W + (size_t)k * 512 + sc) = vc;
}

// ---- interleaved weights (fallback path): W[2k][s]=cos, W[2k+1][s]=-sin ----
__global__ void build_w_kernel(const float* __restrict__ wsin, const float* __restrict__ wcos,
                               uint16_t* __restrict__ W) {
    int i = blockIdx.x * blockDim.x + threadIdx.x;
    int k = i >> 7;
    int sc = (i & 127) * 8;
    const float4* c = (const float4*)(wcos + (size_t)k * K_DIM + sc);
    const float4* s = (const float4*)(wsin + (size_t)k * K_DIM + sc);
    float4 c0 = c[0], c1 = c[1], s0 = s[0], s1 = s[1];
    u16x8 vc, vs;
    vc[0] = f2bf(c0.x); vc[1] = f2bf(c0.y); vc[2] = f2bf(c0.z); vc[3] = f2bf(c0.w);
    vc[4] = f2bf(c1.x); vc[5] = f2bf(c1.y); vc[6] = f2bf(c1.z); vc[7] = f2bf(c1.w);
    vs[0] = f2bf(-s0.x); vs[1] = f2bf(-s0.y); vs[2] = f2bf(-s0.z); vs[3] = f2bf(-s0.w);
    vs[4] = f2bf(-s1.x); vs[5] = f2bf(-s1.y); vs[6] = f2bf(-s1.z); vs[7] = f2bf(-s1.w);
    *(u16x8*)(W + (size_t)(2 * k) * K_DIM + sc) = vc;
    *(u16x8*)(W + (size_t)(2 * k + 1) * K_DIM + sc) = vs;
}

// =====================================================================
// Y-RESIDENT double-symmetry DCT — 32-row blocks, SINGLE-BUFFERED B,
// 64 KB LDS total -> 2 blocks/CU (R16 intent, with the LDS overflow
// fixed: B needs 512x32 bf16 = 32 KB/buffer, so dbuf cannot fit; instead
// the stage latency is hidden under MFMA via read-to-regs-then-overwrite).
//   out[m][k] = sum_{s<512} y[m,s] W[k,s] + (-1)^k x[m,512];
//   y = s-fold of x;  out[:,1024-k] = out[:,k].
//   Per tile: ds_read frags -> lgkmcnt(0) -> barrier (buffer dead) ->
//   stage B(kt+1) -> MFMA on regs (covers DMA; W is L2-resident) ->
//   vmcnt(0) -> barrier.
// =====================================================================
__global__ __launch_bounds__(512, 4) void dft_dct32(const float* __restrict__ X,
                                                    const uint16_t* __restrict__ Wq,
                                                    float* __restrict__ C) {
    constexpr int NKT = 16;             // s-tiles of 32 over K=512
    __shared__ uint16_t lds[32768];     // y[32][512] @0 (32 KB); B buf @elem 16384 (32 KB)

    const int t = threadIdx.x;
    const int l = t & 63;
    const int wid = t >> 6;             // 0..7
    const int wm = (wid >> 2) * 16;     // m-half {0,16}
    const int wk = (wid & 3) * 128;     // k-quarter {0,128,256,384}
    const int lr = l & 15;
    const int lhi = l >> 4;

    const int bm = blockIdx.x * 32;

    // ---- B staging (R15-proven mapping): chunk c = i*512+t ->
    //      krow = i*128+(t>>2), slot = t&3; pre-swizzled slot' = (t&3)^((t>>3)&3) ----
    const int kB = t >> 2;
    const int slotB = (t & 3) ^ ((t >> 3) & 3);
    const uint16_t* gB0 = Wq + (size_t)kB * 512 + slotB * 8;
    const int ldsB0 = (t & ~63) * 16;   // wave-uniform byte base within i-group (8 KB each)

    auto stageB = [&](int kt) {
        const int k0 = kt * 32;
#pragma unroll
        for (int i = 0; i < 4; ++i)
            __builtin_amdgcn_global_load_lds(
                (const __attribute__((address_space(1))) void*)(gB0 + (size_t)i * 128 * 512 + k0),
                (__attribute__((address_space(3))) void*)((char*)&lds[16384] + i * 8192 + ldsB0),
                16, 0, 0);
    };

    // ---- stage y ONCE: fold x -> bf16, swizzled.  Thread t covers rows
    //      (t>>6) + 8i (i=0..3), slot t&63. ----
    const int r8 = t >> 6;              // row base 0..7
    const int sl = t & 63;              // slot 0..63
    const int S0 = sl * 8;
    float nyq[4];

    stageB(0);   // W tile 0 DMA lands under the fold (disjoint LDS region)
    {
#pragma unroll
        for (int i = 0; i < 4; ++i) {
            const int r = r8 + 8 * i;
            const float* xr = X + (size_t)(bm + r) * K_DIM;
            const float* pf = xr + S0;
            float4 f0 = *(const float4*)pf;
            float4 f1 = *(const float4*)(pf + 4);
            const float* pm = xr + (1016 - S0);
            float4 m0 = *(const float4*)pm;
            float4 m1 = *(const float4*)(pm + 4);
            float rsv = pm[(S0 == 0) ? 0 : 8];  // x[1024-S0]; safe dummy at S0==0
            float y0 = f0.x + ((S0 == 0) ? 0.f : rsv);
            float y1 = f0.y + m1.w;
            float y2 = f0.z + m1.z;
            float y3 = f0.w + m1.y;
            float y4 = f1.x + m1.x;
            float y5 = f1.y + m0.w;
            float y6 = f1.z + m0.z;
            float y7 = f1.w + m0.y;
            union { u16x8 v; uint32_t u32[4]; } u;
            asm("v_cvt_pk_bf16_f32 %0, %1, %2" : "=v"(u.u32[0]) : "v"(y0), "v"(y1));
            asm("v_cvt_pk_bf16_f32 %0, %1, %2" : "=v"(u.u32[1]) : "v"(y2), "v"(y3));
            asm("v_cvt_pk_bf16_f32 %0, %1, %2" : "=v"(u.u32[2]) : "v"(y4), "v"(y5));
            asm("v_cvt_pk_bf16_f32 %0, %1, %2" : "=v"(u.u32[3]) : "v"(y6), "v"(y7));
            const int slp = sl ^ (r & 7);        // y swizzle
            *(u16x8*)&lds[r * 512 + slp * 8] = u.v;
            nyq[i] = (y0 - y1) + (y2 - y3) + (y4 - y5) + (y6 - y7);  // (-1)^s partial
        }
    }
    __builtin_amdgcn_sched_barrier(0);
    asm volatile("s_waitcnt vmcnt(0)" ::: "memory");    // B(0) + x loads done
    asm volatile("s_waitcnt lgkmcnt(0)" ::: "memory");  // y writes visible
    __builtin_amdgcn_s_barrier();
    __builtin_amdgcn_sched_barrier(0);

    // ---- main loop: y resident; single B buffer; stage hidden under MFMA ----
    f32x4 acc[8] = {};
    const uint16_t* bB = &lds[16384];
    for (int kt = 0; kt < NKT; ++kt) {
        // read everything this wave needs from the buffer into regs
        bf16x8 af, bf[8];
        {
            const int row = wm + lr;
            const int slp = (kt * 4 + lhi) ^ (row & 7);
            af = *(const bf16x8*)&lds[row * 512 + slp * 8];
        }
#pragma unroll
        for (int ni = 0; ni < 8; ++ni) {
            const int krow = wk + ni * 16 + lr;
            const int slp = lhi ^ ((krow >> 1) & 3);
            bf[ni] = *(const bf16x8*)&bB[krow * 32 + slp * 8];
        }
        __builtin_amdgcn_sched_barrier(0);
        asm volatile("s_waitcnt lgkmcnt(0)" ::: "memory");  // reads retired -> buffer dead
        __builtin_amdgcn_s_barrier();
        __builtin_amdgcn_sched_barrier(0);

        stageB((kt + 1) & 15);              // overwrite buffer; wrap keeps counts uniform
        __builtin_amdgcn_sched_barrier(0);

        __builtin_amdgcn_s_setprio(1);
#pragma unroll
        for (int ni = 0; ni < 8; ++ni)
            acc[ni] = __builtin_amdgcn_mfma_f32_16x16x32_bf16(af, bf[ni], acc[ni], 0, 0, 0);
        __builtin_amdgcn_s_setprio(0);

        __builtin_amdgcn_sched_barrier(0);
        asm volatile("s_waitcnt vmcnt(0)" ::: "memory");    // B(kt+1) landed
        __builtin_amdgcn_s_barrier();
        __builtin_amdgcn_sched_barrier(0);
    }

    // ---- Nyquist (col 512) + x512 vector; y region dead after last barrier ----
    float* nl = (float*)&lds[0];        // 32 rows x 64 slots f32 (8 KB)
    float* l512 = (float*)&lds[4096];   // 32 f32 @ byte 8192
#pragma unroll
    for (int i = 0; i < 4; ++i) nl[(r8 + 8 * i) * 64 + sl] = nyq[i];
    if (t < 32) l512[t] = X[(size_t)(bm + t) * K_DIM + 512];
    __syncthreads();
    if (t < 32) {
        float s = 0.f;
#pragma unroll
        for (int j = 0; j < 64; ++j) s += nl[t * 64 + j];
        C[(size_t)(bm + t) * 1024 + 512] = s + l512[t];
    }

    // ---- epilogue: v = acc + (-1)^k x512; straight col k + mirror 1024-k ----
    const int cr = lhi * 4;
    const float sg = (lr & 1) ? -1.f : 1.f;      // col parity == lr&1
#pragma unroll
    for (int j = 0; j < 4; ++j) {
        const int rowL = wm + cr + j;
        const float corr = sg * l512[rowL];
        const size_t base = (size_t)(bm + rowL) * 1024;
#pragma unroll
        for (int ni = 0; ni < 8; ++ni) {
            const int col = wk + ni * 16 + lr;
            const float v = acc[ni][j] + corr;
            C[base + col] = v;
            if (col) C[base + 1024 - col] = v;   // k=0 has no mirror
        }
    }
}

// ---- 128x128 gload_lds GEMM (fallback for the interleaved/2048 path) ----
template <int NDIM>
__global__ __launch_bounds__(256) void dft_gemm128(const uint16_t* __restrict__ A,
                                                   const uint16_t* __restrict__ B,
                                                   float* __restrict__ C,
                                                   long long out_elems) {
    constexpr int NT = NDIM / BN;
    __shared__ uint16_t As[BM * BK];
    __shared__ uint16_t Bs[BN * BK];

    const int t = threadIdx.x;
    const int l = t & 63;
    const int w = t >> 6;

    int bid = blockIdx.x;
    {
        int nwg = gridDim.x;
        if ((nwg & 7) == 0) { int q = nwg >> 3; bid = (bid & 7) * q + (bid >> 3); }
    }
    const int bm = (bid / NT) * BM;
    const int bn = (bid % NT) * BN;

    const uint16_t* gA[4];
    const uint16_t* gB[4];
    int ldsOff[4];
#pragma unroll
    for (int i = 0; i < 4; ++i) {
        int chunk = i * 256 + t;
        int row = chunk >> 3;
        int cc = (chunk & 7) * 8;
        gA[i] = A + (size_t)(bm + row) * K_DIM + cc;
        gB[i] = B + (size_t)(bn + row) * K_DIM + cc;
        ldsOff[i] = (i * 256 + (t & 192)) * 16;
    }

    const int wm = ((w >> 1) & 1) * 64;
    const int wn = (w & 1) * 64;
    const int lr = l & 15;
    const int lk = (l >> 4) * 8;

    f32x4 acc[4][4] = {};

    for (int k0 = 0; k0 < K_DIM; k0 += BK) {
#pragma unroll
        for (int i = 0; i < 4; ++i)
            __builtin_amdgcn_global_load_lds(
                (const __attribute__((address_space(1))) void*)(gA[i] + k0),
                (__attribute__((address_space(3))) void*)((char*)As + ldsOff[i]), 16, 0, 0);
#pragma unroll
        for (int i = 0; i < 4; ++i)
            __builtin_amdgcn_global_load_lds(
                (const __attribute__((address_space(1))) void*)(gB[i] + k0),
                (__attribute__((address_space(3))) void*)((char*)Bs + ldsOff[i]), 16, 0, 0);
        __syncthreads();
#pragma unroll
        for (int kk = 0; kk < BK; kk += 32) {
            bf16x8 af[4], bfr[4];
#pragma unroll
            for (int m = 0; m < 4; ++m)
                af[m] = *(const bf16x8*)&As[(wm + m * 16 + lr) * BK + kk + lk];
#pragma unroll
            for (int n = 0; n < 4; ++n)
                bfr[n] = *(const bf16x8*)&Bs[(wn + n * 16 + lr) * BK + kk + lk];
#pragma unroll
            for (int m = 0; m < 4; ++m)
#pragma unroll
                for (int n = 0; n < 4; ++n)
                    acc[m][n] = __builtin_amdgcn_mfma_f32_16x16x32_bf16(af[m], bfr[n],
                                                                        acc[m][n], 0, 0, 0);
        }
        __syncthreads();
    }

    const int cr = (l >> 4) * 4;
    const bool safe = ((long long)(bm + BM) * NDIM) <= out_elems;
    if (safe) {
#pragma unroll
        for (int m = 0; m < 4; ++m) {
            int grow = bm + wm + m * 16 + cr;
#pragma unroll
            for (int j = 0; j < 4; ++j) {
                float* cp = C + (size_t)(grow + j) * NDIM + bn + wn + lr;
#pragma unroll
                for (int n = 0; n < 4; ++n)
                    cp[n * 16] = acc[m][n][j];
            }
        }
    } else {
        for (int m = 0; m < 4; ++m) {
            int grow = bm + wm + m * 16 + cr;
            for (int j = 0; j < 4; ++j) {
                long long base = (long long)(grow + j) * NDIM + bn + wn + lr;
                for (int n = 0; n < 4; ++n)
                    if (base + n * 16 < out_elems) C[base + n * 16] = acc[m][n][j];
            }
        }
    }
}

// ---- fp32 fallback (only if ws too small) ----
__global__ void dft_naive(const float* __restrict__ x, const float* __restrict__ wsin,
                          const float* __restrict__ wcos, float* __restrict__ out,
                          long long out_elems, int real_only) {
    __shared__ float xs[K_DIM];
    int row = blockIdx.x;
    const float* xr = x + (size_t)row * K_DIM;
    for (int i = threadIdx.x; i < K_DIM; i += blockDim.x) xs[i] = xr[i];
    __syncthreads();
    for (int k = threadIdx.x; k < K_DIM; k += blockDim.x) {
        const float* wc = wcos + (size_t)k * K_DIM;
        float re = 0.f;
        if (real_only) {
            for (int s = 0; s < K_DIM; ++s) re += xs[s] * wc[s];
            long long o = (long long)row * K_DIM + k;
            if (o < out_elems) out[o] = re;
        } else {
            const float* ws = wsin + (size_t)k * K_DIM;
            float im = 0.f;
            for (int s = 0; s < K_DIM; ++s) { re += xs[s] * wc[s]; im += xs[s] * ws[s]; }
            long long o = ((long long)row * K_DIM + k) * 2;
            if (o + 1 < out_elems) { out[o] = re; out[o + 1] = -im; }
        }
    }
}

extern "C" void kernel_launch(void* const* d_in, const int* in_sizes, int n_in,
                              void* d_out, int out_size, void* d_ws, size_t ws_size,
                              hipStream_t stream) {
    const float* x    = (const float*)d_in[0];
    const float* wsin = (const float*)d_in[1];
    const float* wcos = (const float*)d_in[2];
    float* out = (float*)d_out;

    const int real_only = (out_size == M_TOT * 1024);
    const size_t need = (size_t)M_TOT * K_DIM * 2 + (size_t)2048 * K_DIM * 2;

    if (ws_size >= need) {
        uint16_t* xb = (uint16_t*)d_ws;
        uint16_t* Wb = xb + (size_t)M_TOT * K_DIM;
        if (real_only) {
            build_wq_kernel<<<128, 256, 0, stream>>>(wcos, Wb);   // 512x512 quarter-W
            dft_dct32<<<M_TOT / 32, 512, 0, stream>>>(x, Wb, out);
        } else {
            cvt_x_kernel<<<2048, 256, 0, stream>>>(x, xb);
            build_w_kernel<<<512, 256, 0, stream>>>(wsin, wcos, Wb);
            dft_gemm128<2048><<<128 * 16, 256, 0, stream>>>(xb, Wb, out, (long long)out_size);
        }
    } else {
        dft_naive<<<M_TOT, 256, 0, stream>>>(x, wsin, wcos, out, (long long)out_size,
                                             real_only);
    }
}

// Round 18
// 42.221 us; speedup vs baseline: 1.0938x; 1.0938x over previous
//
#include <hip/hip_runtime.h>
#include <stdint.h>

#define K_DIM 1024
#define M_TOT 16384
#define BM 128
#define BN 128
#define BK 64

typedef __attribute__((ext_vector_type(8))) short bf16x8;
typedef __attribute__((ext_vector_type(4))) float f32x4;
typedef __attribute__((ext_vector_type(8))) unsigned short u16x8;

__device__ inline uint16_t f2bf(float f) {
    union { float f; uint32_t u; } v; v.f = f;
    return (uint16_t)((v.u + 0x7fffu + ((v.u >> 16) & 1u)) >> 16);
}

// ---- x (16M f32) -> bf16 (only used by the 2048 fallback path) ----
__global__ void cvt_x_kernel(const float* __restrict__ x, uint16_t* __restrict__ xb) {
    const size_t n8 = (size_t)M_TOT * K_DIM / 8;
    for (size_t i = (size_t)blockIdx.x * blockDim.x + threadIdx.x; i < n8;
         i += (size_t)gridDim.x * blockDim.x) {
        const float4* s = (const float4*)x + i * 2;
        float4 a = s[0], b = s[1];
        u16x8 v;
        v[0] = f2bf(a.x); v[1] = f2bf(a.y); v[2] = f2bf(a.z); v[3] = f2bf(a.w);
        v[4] = f2bf(b.x); v[5] = f2bf(b.y); v[6] = f2bf(b.z); v[7] = f2bf(b.w);
        *(u16x8*)(xb + i * 8) = v;
    }
}

// ---- quarter weights: W[k][s] = cos(2*pi*k*s/1024), k,s in [0,512) ----
__global__ void build_wq_kernel(const float* __restrict__ wcos, uint16_t* __restrict__ W) {
    int i = blockIdx.x * blockDim.x + threadIdx.x;   // 32768 threads
    int k = i >> 6;            // 512 rows
    int sc = (i & 63) * 8;     // cols 0..511
    const float4* c = (const float4*)(wcos + (size_t)k * K_DIM + sc);
    float4 c0 = c[0], c1 = c[1];
    u16x8 vc;
    vc[0] = f2bf(c0.x); vc[1] = f2bf(c0.y); vc[2] = f2bf(c0.z); vc[3] = f2bf(c0.w);
    vc[4] = f2bf(c1.x); vc[5] = f2bf(c1.y); vc[6] = f2bf(c1.z); vc[7] = f2bf(c1.w);
    *(u16x8*)(W + (size_t)k * 512 + sc) = vc;
}

// ---- interleaved weights (fallback path): W[2k][s]=cos, W[2k+1][s]=-sin ----
__global__ void build_w_kernel(const float* __restrict__ wsin, const float* __restrict__ wcos,
                               uint16_t* __restrict__ W) {
    int i = blockIdx.x * blockDim.x + threadIdx.x;
    int k = i >> 7;
    int sc = (i & 127) * 8;
    const float4* c = (const float4*)(wcos + (size_t)k * K_DIM + sc);
    const float4* s = (const float4*)(wsin + (size_t)k * K_DIM + sc);
    float4 c0 = c[0], c1 = c[1], s0 = s[0], s1 = s[1];
    u16x8 vc, vs;
    vc[0] = f2bf(c0.x); vc[1] = f2bf(c0.y); vc[2] = f2bf(c0.z); vc[3] = f2bf(c0.w);
    vc[4] = f2bf(c1.x); vc[5] = f2bf(c1.y); vc[6] = f2bf(c1.z); vc[7] = f2bf(c1.w);
    vs[0] = f2bf(-s0.x); vs[1] = f2bf(-s0.y); vs[2] = f2bf(-s0.z); vs[3] = f2bf(-s0.w);
    vs[4] = f2bf(-s1.x); vs[5] = f2bf(-s1.y); vs[6] = f2bf(-s1.z); vs[7] = f2bf(-s1.w);
    *(u16x8*)(W + (size_t)(2 * k) * K_DIM + sc) = vc;
    *(u16x8*)(W + (size_t)(2 * k + 1) * K_DIM + sc) = vs;
}

// =====================================================================
// Kernel 1: FOLD (pure streaming).  One wave per row.
//   y[m,s] = x[m,s] + x[m,1024-s] (s>=1), y[m,0] = x[m,0]; bf16,
//   written PRE-SWIZZLED: position p in each 8-chunk group holds
//   chunk p^(row&7), so the GEMM stages linearly and ds_reads with
//   slot^(row&7) (rule-21 pair).  Also: C[m,512] = sum_s y*(-1)^s +
//   x[m,512] via wave shfl-reduce (cos(pi*s) column).
// =====================================================================
__global__ __launch_bounds__(256) void fold_kernel(const float* __restrict__ X,
                                                   uint16_t* __restrict__ Y,
                                                   float* __restrict__ C) {
    const int w = threadIdx.x >> 6;
    const int ln = threadIdx.x & 63;
    const int row = blockIdx.x * 4 + w;
    const float* xr = X + (size_t)row * K_DIM;
    const int S0 = ln * 8;

    float4 f0 = *(const float4*)(xr + S0);
    float4 f1 = *(const float4*)(xr + S0 + 4);
    const float* pm = xr + (1016 - S0);
    float4 m0 = *(const float4*)pm;
    float4 m1 = *(const float4*)(pm + 4);
    float rsv = pm[(S0 == 0) ? 0 : 8];          // x[1024-S0]; dummy at S0==0

    float y0 = f0.x + ((S0 == 0) ? 0.f : rsv);
    float y1 = f0.y + m1.w;
    float y2 = f0.z + m1.z;
    float y3 = f0.w + m1.y;
    float y4 = f1.x + m1.x;
    float y5 = f1.y + m0.w;
    float y6 = f1.z + m0.z;
    float y7 = f1.w + m0.y;

    union { u16x8 v; uint32_t u32[4]; } u;
    asm("v_cvt_pk_bf16_f32 %0, %1, %2" : "=v"(u.u32[0]) : "v"(y0), "v"(y1));
    asm("v_cvt_pk_bf16_f32 %0, %1, %2" : "=v"(u.u32[1]) : "v"(y2), "v"(y3));
    asm("v_cvt_pk_bf16_f32 %0, %1, %2" : "=v"(u.u32[2]) : "v"(y4), "v"(y5));
    asm("v_cvt_pk_bf16_f32 %0, %1, %2" : "=v"(u.u32[3]) : "v"(y6), "v"(y7));

    const int sw = (ln & ~7) | ((ln & 7) ^ (row & 7));      // pre-swizzle chunk pos
    *(u16x8*)(Y + (size_t)row * 512 + sw * 8) = u.v;

    // Nyquist: sum_s y[s]*(-1)^s  (chunk parity alternates within the 8)
    float nyq = (y0 - y1) + (y2 - y3) + (y4 - y5) + (y6 - y7);
#pragma unroll
    for (int off = 1; off < 64; off <<= 1) nyq += __shfl_xor(nyq, off, 64);
    if (ln == 0) C[(size_t)row * K_DIM + 512] = nyq + xr[512];
}

// =====================================================================
// Kernel 2: minimal GEMM from pre-folded y.
//   out[m][k] = sum_{s<512} y[m,s] Wq[k,s] + (-1)^k x[m,512], k in [0,512);
//   mirror write out[:,1024-k] = out[:,k].
//   R4-proven structure: BOTH operands via global_load_lds (A source
//   linear — Y is pre-swizzled in memory; B source pre-swizzled here),
//   dbuf 64 KB -> 2 blocks/CU, 8 K-tiles, R9 single-barrier ledger,
//   T1 bijective XCD swizzle (grid 512).
// =====================================================================
__global__ __launch_bounds__(256, 2) void dft_gemm_y(const uint16_t* __restrict__ Y,
                                                     const uint16_t* __restrict__ Wq,
                                                     const float* __restrict__ X,
                                                     float* __restrict__ C) {
    constexpr int NKT = 8;                       // K = 512, BK = 64
    __shared__ uint16_t lds[2][2][BM * BK];      // [dbuf][A/B][128*64] = 64 KiB
    __shared__ float l512[BM];

    const int t = threadIdx.x;
    const int l = t & 63;
    const int w = t >> 6;
    const int wm = (w >> 1) * 64;
    const int wn = (w & 1) * 64;
    const int lr = l & 15;
    const int lhi = l >> 4;
    const int xr7 = lr & 7;

    // T1: bijective XCD swizzle (nwg = 512; q = 64). The 4 n-blocks sharing
    // an A panel are consecutive -> same XCD.
    int bid = blockIdx.x;
    {
        int nwg = gridDim.x;
        if ((nwg & 7) == 0) { int q = nwg >> 3; bid = (bid & 7) * q + (bid >> 3); }
    }
    const int bm = (bid >> 2) * BM;
    const int bn = (bid & 3) * 128;              // GEMM cols [bn, bn+128)

    // staging: 1024 chunks of 16 B = [128 rows][8 slots]; thread t covers
    // rows r0 + i*32 (i=0..3), slot sl.  A source LINEAR (Y pre-swizzled);
    // B source pre-swizzled (slot sl ^ (r&7)); LDS dests linear.
    const int r0 = t >> 3, sl = t & 7;
    const int swsl = sl ^ (r0 & 7);
    const uint16_t* gA0 = Y + (size_t)(bm + r0) * 512 + sl * 8;
    const uint16_t* gB0 = Wq + (size_t)(bn + r0) * 512 + swsl * 8;
    const int ldsOff = (t & 192) * 16;           // wave-uniform; HW adds lane*16

    auto stage = [&](int d, int kt) {
        const int k0 = kt * BK;
#pragma unroll
        for (int i = 0; i < 4; ++i)
            __builtin_amdgcn_global_load_lds(
                (const __attribute__((address_space(1))) void*)(gA0 + (size_t)i * 32 * 512 + k0),
                (__attribute__((address_space(3))) void*)((char*)&lds[d][0][0] + i * 4096 + ldsOff),
                16, 0, 0);
#pragma unroll
        for (int i = 0; i < 4; ++i)
            __builtin_amdgcn_global_load_lds(
                (const __attribute__((address_space(1))) void*)(gB0 + (size_t)i * 32 * 512 + k0),
                (__attribute__((address_space(3))) void*)((char*)&lds[d][1][0] + i * 4096 + ldsOff),
                16, 0, 0);
    };
    auto loadFrag = [&](const uint16_t* buf, int row, int kk) -> bf16x8 {
        int s = (kk >> 3) + lhi;
        return *(const bf16x8*)(buf + row * 64 + ((s ^ xr7) * 8));
    };

    f32x4 acc[4][4] = {};

    // prologue: tile 0
    stage(0, 0);
    __builtin_amdgcn_sched_barrier(0);
    asm volatile("s_waitcnt vmcnt(0)" ::: "memory");
    __builtin_amdgcn_s_barrier();
    __builtin_amdgcn_sched_barrier(0);

    for (int kt = 0; kt < NKT; ++kt) {
        const int cc = kt & 1;
        const uint16_t* bA = &lds[cc][0][0];
        const uint16_t* bB = &lds[cc][1][0];
        int ktn = kt + 1; if (ktn >= NKT) ktn -= NKT;     // wrap: uniform counts
        stage(1 - cc, ktn);                               // buf freed by prev barrier
        __builtin_amdgcn_sched_barrier(0);

#pragma unroll
        for (int ks = 0; ks < 2; ++ks) {
            const int kk = ks * 32;
            bf16x8 af[4], bfr[4];
#pragma unroll
            for (int n = 0; n < 4; ++n) bfr[n] = loadFrag(bB, wn + n * 16 + lr, kk);
#pragma unroll
            for (int m = 0; m < 4; ++m) af[m] = loadFrag(bA, wm + m * 16 + lr, kk);
#pragma unroll
            for (int m = 0; m < 4; ++m)
#pragma unroll
                for (int n = 0; n < 4; ++n)
                    acc[m][n] = __builtin_amdgcn_mfma_f32_16x16x32_bf16(af[m], bfr[n],
                                                                        acc[m][n], 0, 0, 0);
        }

        // boundary: next tile's DMA landed; this wave's reads consumed (MFMA).
        __builtin_amdgcn_sched_barrier(0);
        asm volatile("s_waitcnt vmcnt(0)" ::: "memory");
        __builtin_amdgcn_s_barrier();
        __builtin_amdgcn_sched_barrier(0);
    }

    // x512 per row for the (-1)^k correction
    if (t < BM) l512[t] = X[(size_t)(bm + t) * K_DIM + 512];
    __syncthreads();

    // epilogue: v = acc + (-1)^k x512; straight col + mirror 1024-col
    const int cr = lhi * 4;
    const float sg = (lr & 1) ? -1.f : 1.f;      // col parity == lr&1
#pragma unroll
    for (int m = 0; m < 4; ++m) {
#pragma unroll
        for (int j = 0; j < 4; ++j) {
            const int rowL = wm + m * 16 + cr + j;
            const float corr = sg * l512[rowL];
            const size_t base = (size_t)(bm + rowL) * K_DIM;
#pragma unroll
            for (int n = 0; n < 4; ++n) {
                const int col = bn + wn + n * 16 + lr;
                const float v = acc[m][n][j] + corr;
                C[base + col] = v;
                if (col) C[base + 1024 - col] = v;   // k=0 has no mirror
            }
        }
    }
}

// ---- 128x128 gload_lds GEMM (fallback for the interleaved/2048 path) ----
template <int NDIM>
__global__ __launch_bounds__(256) void dft_gemm128(const uint16_t* __restrict__ A,
                                                   const uint16_t* __restrict__ B,
                                                   float* __restrict__ C,
                                                   long long out_elems) {
    constexpr int NT = NDIM / BN;
    __shared__ uint16_t As[BM * BK];
    __shared__ uint16_t Bs[BN * BK];

    const int t = threadIdx.x;
    const int l = t & 63;
    const int w = t >> 6;

    int bid = blockIdx.x;
    {
        int nwg = gridDim.x;
        if ((nwg & 7) == 0) { int q = nwg >> 3; bid = (bid & 7) * q + (bid >> 3); }
    }
    const int bm = (bid / NT) * BM;
    const int bn = (bid % NT) * BN;

    const uint16_t* gA[4];
    const uint16_t* gB[4];
    int ldsOff[4];
#pragma unroll
    for (int i = 0; i < 4; ++i) {
        int chunk = i * 256 + t;
        int row = chunk >> 3;
        int cc = (chunk & 7) * 8;
        gA[i] = A + (size_t)(bm + row) * K_DIM + cc;
        gB[i] = B + (size_t)(bn + row) * K_DIM + cc;
        ldsOff[i] = (i * 256 + (t & 192)) * 16;
    }

    const int wm = ((w >> 1) & 1) * 64;
    const int wn = (w & 1) * 64;
    const int lr = l & 15;
    const int lk = (l >> 4) * 8;

    f32x4 acc[4][4] = {};

    for (int k0 = 0; k0 < K_DIM; k0 += BK) {
#pragma unroll
        for (int i = 0; i < 4; ++i)
            __builtin_amdgcn_global_load_lds(
                (const __attribute__((address_space(1))) void*)(gA[i] + k0),
                (__attribute__((address_space(3))) void*)((char*)As + ldsOff[i]), 16, 0, 0);
#pragma unroll
        for (int i = 0; i < 4; ++i)
            __builtin_amdgcn_global_load_lds(
                (const __attribute__((address_space(1))) void*)(gB[i] + k0),
                (__attribute__((address_space(3))) void*)((char*)Bs + ldsOff[i]), 16, 0, 0);
        __syncthreads();
#pragma unroll
        for (int kk = 0; kk < BK; kk += 32) {
            bf16x8 af[4], bfr[4];
#pragma unroll
            for (int m = 0; m < 4; ++m)
                af[m] = *(const bf16x8*)&As[(wm + m * 16 + lr) * BK + kk + lk];
#pragma unroll
            for (int n = 0; n < 4; ++n)
                bfr[n] = *(const bf16x8*)&Bs[(wn + n * 16 + lr) * BK + kk + lk];
#pragma unroll
            for (int m = 0; m < 4; ++m)
#pragma unroll
                for (int n = 0; n < 4; ++n)
                    acc[m][n] = __builtin_amdgcn_mfma_f32_16x16x32_bf16(af[m], bfr[n],
                                                                        acc[m][n], 0, 0, 0);
        }
        __syncthreads();
    }

    const int cr = (l >> 4) * 4;
    const bool safe = ((long long)(bm + BM) * NDIM) <= out_elems;
    if (safe) {
#pragma unroll
        for (int m = 0; m < 4; ++m) {
            int grow = bm + wm + m * 16 + cr;
#pragma unroll
            for (int j = 0; j < 4; ++j) {
                float* cp = C + (size_t)(grow + j) * NDIM + bn + wn + lr;
#pragma unroll
                for (int n = 0; n < 4; ++n)
                    cp[n * 16] = acc[m][n][j];
            }
        }
    } else {
        for (int m = 0; m < 4; ++m) {
            int grow = bm + wm + m * 16 + cr;
            for (int j = 0; j < 4; ++j) {
                long long base = (long long)(grow + j) * NDIM + bn + wn + lr;
                for (int n = 0; n < 4; ++n)
                    if (base + n * 16 < out_elems) C[base + n * 16] = acc[m][n][j];
            }
        }
    }
}

// ---- fp32 fallback (only if ws too small) ----
__global__ void dft_naive(const float* __restrict__ x, const float* __restrict__ wsin,
                          const float* __restrict__ wcos, float* __restrict__ out,
                          long long out_elems, int real_only) {
    __shared__ float xs[K_DIM];
    int row = blockIdx.x;
    const float* xr = x + (size_t)row * K_DIM;
    for (int i = threadIdx.x; i < K_DIM; i += blockDim.x) xs[i] = xr[i];
    __syncthreads();
    for (int k = threadIdx.x; k < K_DIM; k += blockDim.x) {
        const float* wc = wcos + (size_t)k * K_DIM;
        float re = 0.f;
        if (real_only) {
            for (int s = 0; s < K_DIM; ++s) re += xs[s] * wc[s];
            long long o = (long long)row * K_DIM + k;
            if (o < out_elems) out[o] = re;
        } else {
            const float* ws = wsin + (size_t)k * K_DIM;
            float im = 0.f;
            for (int s = 0; s < K_DIM; ++s) { re += xs[s] * wc[s]; im += xs[s] * ws[s]; }
            long long o = ((long long)row * K_DIM + k) * 2;
            if (o + 1 < out_elems) { out[o] = re; out[o + 1] = -im; }
        }
    }
}

extern "C" void kernel_launch(void* const* d_in, const int* in_sizes, int n_in,
                              void* d_out, int out_size, void* d_ws, size_t ws_size,
                              hipStream_t stream) {
    const float* x    = (const float*)d_in[0];
    const float* wsin = (const float*)d_in[1];
    const float* wcos = (const float*)d_in[2];
    float* out = (float*)d_out;

    const int real_only = (out_size == M_TOT * 1024);
    const size_t need = (size_t)M_TOT * K_DIM * 2 + (size_t)2048 * K_DIM * 2;

    if (ws_size >= need) {
        uint16_t* Yb = (uint16_t*)d_ws;                       // 16 MB (M x 512 bf16)
        uint16_t* Wb = Yb + (size_t)M_TOT * 512;              // 512 KB quarter-W
        if (real_only) {
            build_wq_kernel<<<128, 256, 0, stream>>>(wcos, Wb);
            fold_kernel<<<M_TOT / 4, 256, 0, stream>>>(x, Yb, out);
            dft_gemm_y<<<(M_TOT / 128) * 4, 256, 0, stream>>>(Yb, Wb, x, out);
        } else {
            uint16_t* xb = (uint16_t*)d_ws;
            uint16_t* Wb2 = xb + (size_t)M_TOT * K_DIM;
            cvt_x_kernel<<<2048, 256, 0, stream>>>(x, xb);
            build_w_kernel<<<512, 256, 0, stream>>>(wsin, wcos, Wb2);
            dft_gemm128<2048><<<128 * 16, 256, 0, stream>>>(xb, Wb2, out, (long long)out_size);
        }
    } else {
        dft_naive<<<M_TOT, 256, 0, stream>>>(x, wsin, wcos, out, (long long)out_size,
                                             real_only);
    }
}